// Round 2
// baseline (1897.460 us; speedup 1.0000x reference)
//
#include <hip/hip_runtime.h>

#define NN 100000
#define EE 1600000
#define FF 128
#define LL 4
#define GG 512
#define OUTC 10
#define EPSF 1e-5f
#define NSCB ((NN + 255) / 256)   // 391 scan blocks

// k_agg geometry: each wave owns NPW contiguous nodes => contiguous CSR edge range
#define NPW 8
#define AGG_WAVES ((NN + NPW - 1) / NPW)
#define AGG_BLOCKS ((AGG_WAVES + 3) / 4)

typedef __attribute__((ext_vector_type(8))) short short8;
typedef __attribute__((ext_vector_type(4))) float f32x4;

__device__ inline unsigned bf16rne(float f) {
  unsigned u = __float_as_uint(f);
  return (u + 0x7fffu + ((u >> 16) & 1u)) >> 16;
}
__device__ inline unsigned packbf(float lo, float hi) {
  return bf16rne(lo) | (bf16rne(hi) << 16);
}
__device__ inline float bflo(unsigned u) { return __uint_as_float(u << 16); }
__device__ inline float bfhi(unsigned u) { return __uint_as_float(u & 0xffff0000u); }

// ---------- graph setup ----------

__global__ __launch_bounds__(256) void k_deg(const int* __restrict__ col, int* __restrict__ deg) {
  int e = blockIdx.x * 256 + threadIdx.x;
  if (e < EE) atomicAdd(&deg[col[e]], 1);
}

__global__ __launch_bounds__(256) void k_dinv(const int* __restrict__ deg, float* __restrict__ dinv) {
  int n = blockIdx.x * 256 + threadIdx.x;
  if (n < NN) {
    int d = deg[n];
    dinv[n] = d > 0 ? rsqrtf((float)d) : 0.0f;
  }
}

// per-block degree sums (391 blocks x 256)
__global__ __launch_bounds__(256) void k_bsum(const int* __restrict__ deg, int* __restrict__ bsum) {
  int i = blockIdx.x * 256 + threadIdx.x;
  int v = (i < NN) ? deg[i] : 0;
#pragma unroll
  for (int off = 32; off > 0; off >>= 1) v += __shfl_down(v, off, 64);
  __shared__ int ws[4];
  if ((threadIdx.x & 63) == 0) ws[threadIdx.x >> 6] = v;
  __syncthreads();
  if (threadIdx.x == 0) bsum[blockIdx.x] = ws[0] + ws[1] + ws[2] + ws[3];
}

// each block: scan all block sums in LDS (redundant), local scan of its 256 degs,
// write exclusive rowptr. rowptr[NN] = EE (constant).
__global__ __launch_bounds__(256) void k_rowptr(const int* __restrict__ deg,
                                                const int* __restrict__ bsum,
                                                int* __restrict__ rowptr) {
  __shared__ int sb[512];
  __shared__ int sd[256];
  const int t = threadIdx.x;
  sb[t]       = (t < NSCB) ? bsum[t] : 0;
  sb[t + 256] = (t + 256 < NSCB) ? bsum[t + 256] : 0;
  __syncthreads();
#pragma unroll
  for (int off = 1; off < 512; off <<= 1) {
    int v0 = (t >= off) ? sb[t - off] : 0;
    int v1 = sb[t + 256 - off];
    __syncthreads();
    sb[t] += v0;
    sb[t + 256] += v1;
    __syncthreads();
  }
  const int bpre = (blockIdx.x == 0) ? 0 : sb[blockIdx.x - 1];
  const int i = blockIdx.x * 256 + t;
  const int d = (i < NN) ? deg[i] : 0;
  sd[t] = d;
  __syncthreads();
#pragma unroll
  for (int off = 1; off < 256; off <<= 1) {
    int v = (t >= off) ? sd[t - off] : 0;
    __syncthreads();
    sd[t] += v;
    __syncthreads();
  }
  if (i < NN) rowptr[i] = bpre + sd[t] - d;
  if (blockIdx.x == 0 && t == 0) rowptr[NN] = EE;
}

// build CSR: one interleaved (src, weight) int2 store per edge.
// Also accumulates swsum[dst] = sum of edge weights into dst (for BN-fold base term).
__global__ __launch_bounds__(256) void k_fill(const int* __restrict__ ei,
                                              const int* __restrict__ rowptr,
                                              int* __restrict__ cnt,
                                              const float* __restrict__ dinv,
                                              int2* __restrict__ ecw,
                                              float* __restrict__ swsum) {
  int e = blockIdx.x * 256 + threadIdx.x;
  if (e >= EE) return;
  int r = ei[e];
  int cl = ei[EE + e];
  float w = dinv[r] * dinv[cl];
  int slot = rowptr[cl] + atomicAdd(&cnt[cl], 1);
  ecw[slot] = make_int2(r, __float_as_int(w));
  atomicAdd(&swsum[cl], w);
}

// batch is sorted: gstart[g] = first node of graph g; gstart[GG] = NN
__global__ __launch_bounds__(256) void k_bounds(const int* __restrict__ batch, int* __restrict__ gstart) {
  int n = blockIdx.x * 256 + threadIdx.x;
  if (n >= NN) return;
  int b = batch[n];
  if (n == 0) {
    for (int g = 0; g <= b; ++g) gstart[g] = 0;
  } else {
    int bp = batch[n - 1];
    for (int g = bp + 1; g <= b; ++g) gstart[g] = n;
  }
  if (n == NN - 1) {
    for (int g = b + 1; g <= GG; ++g) gstart[g] = NN;
  }
}

// ---------- bf16 conversions ----------

// x[N,128] fp32 -> Ab packed bf16 pairs
__global__ __launch_bounds__(256) void k_cvt(const float* __restrict__ x, unsigned* __restrict__ Ab) {
  int i = blockIdx.x * 256 + threadIdx.x;
  if (i < NN * 64) {
    float2 v = *(const float2*)(x + (size_t)i * 2);
    Ab[i] = packbf(v.x, v.y);
  }
}

// W[128,128] fp32 (optionally row-scaled by sc[k] = prev-layer BN scale) -> MFMA
// B-fragments, hi/lo bf16 split. frag index: ((kc*8 + ct)*2 + which), 64 lanes * 16B.
__global__ __launch_bounds__(256) void k_wcvt(const float* __restrict__ W,
                                              const float* __restrict__ sc,   // may be null
                                              uint4* __restrict__ Wf) {
  int tid = blockIdx.x * 256 + threadIdx.x;   // 0..4095
  int lane = tid & 63;
  int which = (tid >> 6) & 1;
  int ct = (tid >> 7) & 7;
  int kc = tid >> 10;
  int n = ct * 16 + (lane & 15);
  int k0 = kc * 32 + (lane >> 4) * 8;
  unsigned h[8];
#pragma unroll
  for (int j = 0; j < 8; ++j) {
    float w = W[(k0 + j) * 128 + n];
    if (sc) w *= sc[k0 + j];
    unsigned hb = bf16rne(w);
    if (which == 0) {
      h[j] = hb;
    } else {
      float hf = __uint_as_float(hb << 16);
      h[j] = bf16rne(w - hf);
    }
  }
  uint4 o;
  o.x = h[0] | (h[1] << 16);
  o.y = h[2] | (h[3] << 16);
  o.z = h[4] | (h[5] << 16);
  o.w = h[6] | (h[7] << 16);
  Wf[tid] = o;
}

// base[c] = sum_k sh[k] * W[k,c]  (sh = bnsc[128..255] of previous layer)
__global__ __launch_bounds__(128) void k_base(const float* __restrict__ W,
                                              const float* __restrict__ bnsc,
                                              float* __restrict__ base) {
  const int c = threadIdx.x;
  float acc = 0.f;
  for (int k = 0; k < 128; ++k) acc = fmaf(bnsc[128 + k], W[k * 128 + c], acc);
  base[c] = acc;
}

// ---------- per-layer GEMM via MFMA: Bb[N,128](packed bf16) = Ab @ (Whi+Wlo) ----------
__global__ __launch_bounds__(256) void k_mm(const unsigned* __restrict__ Ab,
                                            const uint4* __restrict__ Wf,
                                            unsigned* __restrict__ Bb) {
  const int lane = threadIdx.x & 63;
  const int w = threadIdx.x >> 6;
  const int quad = lane >> 4;
  const int m = lane & 15;
  const int rowbase = blockIdx.x * 64 + w * 16;
  const int arow = min(rowbase + m, NN - 1);
  const uint4* A4 = (const uint4*)Ab;
  f32x4 acc[8];
#pragma unroll
  for (int ct = 0; ct < 8; ++ct) acc[ct] = (f32x4){0.f, 0.f, 0.f, 0.f};
#pragma unroll
  for (int kc = 0; kc < 4; ++kc) {
    uint4 av = A4[arow * 16 + kc * 4 + quad];
    short8 af = *(short8*)&av;
#pragma unroll
    for (int ct = 0; ct < 8; ++ct) {
      uint4 bh = Wf[((kc * 8 + ct) * 2 + 0) * 64 + lane];
      uint4 bl = Wf[((kc * 8 + ct) * 2 + 1) * 64 + lane];
      acc[ct] = __builtin_amdgcn_mfma_f32_16x16x32_bf16(af, *(short8*)&bh, acc[ct], 0, 0, 0);
      acc[ct] = __builtin_amdgcn_mfma_f32_16x16x32_bf16(af, *(short8*)&bl, acc[ct], 0, 0, 0);
    }
  }
#pragma unroll
  for (int ct = 0; ct < 8; ++ct) {
#pragma unroll
    for (int r = 0; r < 4; ++r) {
      float v = acc[ct][r];
      float vo = __shfl_xor(v, 1);
      int row = rowbase + quad * 4 + r;
      if ((lane & 1) == 0 && row < NN) {
        Bb[row * 64 + ct * 8 + (m >> 1)] = packbf(v, vo);
      }
    }
  }
}

// ---------- aggregation ----------
// Ar[n] = packbf(relu(sum_e w*B[src] + swsum[n]*base + bias)), BN partial sums,
// and per-graph pooled raw sums (pooling of BN output is affine -> applied in k_z1).
// Each wave owns NPW contiguous nodes => one contiguous CSR edge range.
__global__ __launch_bounds__(256, 8) void k_agg(const unsigned* __restrict__ Bb,
                                                const int* __restrict__ rowptr,
                                                const int2* __restrict__ ecw,
                                                const float* __restrict__ bias,
                                                const float* __restrict__ base,
                                                const float* __restrict__ swsum,
                                                const int* __restrict__ batch,
                                                unsigned* __restrict__ Ar,
                                                float* __restrict__ bnbuf,
                                                float* __restrict__ pooledt) {
  const int lane = threadIdx.x & 63;
  const int wave = threadIdx.x >> 6;
  const int c = lane * 2;
  const int gwave = blockIdx.x * 4 + wave;
  const int n0 = gwave * NPW;
  const float2 bv = *(const float2*)(bias + c);
  const float2 basev = *(const float2*)(base + c);
  float s0 = 0.f, s1 = 0.f, q0 = 0.f, q1 = 0.f;
  __shared__ int srp[4][NPW + 1];
  __shared__ int2 sstage[4][64];
  if (n0 < NN) {
    const int nn = min(NPW, NN - n0);
    if (lane <= nn) srp[wave][lane] = rowptr[n0 + lane];
    int bsp = 0; float swp = 0.f;
    if (lane < nn) { bsp = batch[n0 + lane]; swp = swsum[n0 + lane]; }
    float ax0 = 0.f, ax1 = 0.f, ay0 = 0.f, ay1 = 0.f;
    float px = 0.f, py = 0.f;
    int gprev = -1;
    auto finalize = [&](int node) {
      float sw = __shfl(swp, node);
      float rx = fmaxf(fmaf(sw, basev.x, ax0 + ax1) + bv.x, 0.f);
      float ry = fmaxf(fmaf(sw, basev.y, ay0 + ay1) + bv.y, 0.f);
      Ar[(size_t)(n0 + node) * 64 + lane] = packbf(rx, ry);
      s0 += rx; s1 += ry;
      q0 = fmaf(rx, rx, q0); q1 = fmaf(ry, ry, q1);
      int g = __shfl(bsp, node);
      if (g != gprev) {
        if (gprev >= 0) {
          atomicAdd(&pooledt[(size_t)gprev * 512 + c], px);
          atomicAdd(&pooledt[(size_t)gprev * 512 + c + 1], py);
        }
        gprev = g; px = 0.f; py = 0.f;
      }
      px += rx; py += ry;
      ax0 = 0.f; ax1 = 0.f; ay0 = 0.f; ay1 = 0.f;
    };
    const int beg = __builtin_amdgcn_readfirstlane(srp[wave][0]);
    const int endall = __builtin_amdgcn_readfirstlane(srp[wave][nn]);
    int cn = 0;
    // leading (and possibly all) empty nodes
    while (cn < nn && __builtin_amdgcn_readfirstlane(srp[wave][cn + 1]) == beg) {
      finalize(cn);
      ++cn;
    }
    int nend = (cn < nn) ? __builtin_amdgcn_readfirstlane(srp[wave][cn + 1]) : 0x7fffffff;
    int2 stage = (beg + lane < endall) ? ecw[beg + lane] : make_int2(0, 0);
    for (int base_e = beg; base_e < endall; base_e += 64) {
      sstage[wave][lane] = stage;     // current chunk -> LDS (same-wave, in-order)
      const int nb = base_e + 64;
      if (nb < endall) {              // prefetch next chunk off critical path
        stage = (nb + lane < endall) ? ecw[nb + lane] : make_int2(0, 0);
      }
#pragma unroll
      for (int g = 0; g < 4; ++g) {
        if (base_e + g * 16 < endall) {   // wave-uniform (SGPR) branch
          int2 ew[16]; unsigned us[16];
#pragma unroll
          for (int j = 0; j < 16; ++j) ew[j] = sstage[wave][g * 16 + j];  // broadcast
#pragma unroll
          for (int j = 0; j < 16; ++j) {
            const int sj = __builtin_amdgcn_readfirstlane(ew[j].x);       // SGPR base
            us[j] = Bb[((size_t)(unsigned)sj << 6) + (unsigned)lane];
          }
#pragma unroll
          for (int j = 0; j < 16; ++j) {
            const float wj = __int_as_float(ew[j].y);   // 0 for padding lanes
            if (j & 1) {
              ax1 = fmaf(wj, bflo(us[j]), ax1);
              ay1 = fmaf(wj, bfhi(us[j]), ay1);
            } else {
              ax0 = fmaf(wj, bflo(us[j]), ax0);
              ay0 = fmaf(wj, bfhi(us[j]), ay0);
            }
            const int e1 = base_e + g * 16 + j + 1;     // scalar
            if (e1 == nend) {                           // node boundary (SGPR cmp)
              finalize(cn);
              ++cn;
              nend = (cn < nn) ? __builtin_amdgcn_readfirstlane(srp[wave][cn + 1]) : 0x7fffffff;
              while (cn < nn && nend == e1) {           // empty nodes inside span
                finalize(cn);
                ++cn;
                nend = (cn < nn) ? __builtin_amdgcn_readfirstlane(srp[wave][cn + 1]) : 0x7fffffff;
              }
            }
          }
        }
      }
    }
    if (gprev >= 0) {
      atomicAdd(&pooledt[(size_t)gprev * 512 + c], px);
      atomicAdd(&pooledt[(size_t)gprev * 512 + c + 1], py);
    }
  }
  __shared__ float sred[4][256];
  sred[wave][c] = s0;
  sred[wave][c + 1] = s1;
  sred[wave][128 + c] = q0;
  sred[wave][128 + c + 1] = q1;
  __syncthreads();
  const int t = threadIdx.x;
  float tot = sred[0][t] + sred[1][t] + sred[2][t] + sred[3][t];
  atomicAdd(&bnbuf[t], tot);
}

__global__ __launch_bounds__(128) void k_bnfin(const float* __restrict__ bnbuf,
                                               const float* __restrict__ gamma,
                                               const float* __restrict__ beta,
                                               float* __restrict__ bnsc) {
  const int c = threadIdx.x;
  float mu = bnbuf[c] * (1.0f / NN);
  float var = bnbuf[128 + c] * (1.0f / NN) - mu * mu;
  float inv = rsqrtf(var + EPSF);
  float sc = gamma[c] * inv;
  bnsc[c] = sc;
  bnsc[128 + c] = beta[c] - mu * sc;
}

// ---------- head ----------

// z1 = (affine-pooled) @ W1 + b1 where pooled_gc = sc_c*S_gc + cnt_g*sh_c
__global__ __launch_bounds__(128) void k_z1(const float* __restrict__ S,
                                            const float* __restrict__ bnscL,
                                            const int* __restrict__ gstart,
                                            const float* __restrict__ W1,
                                            const float* __restrict__ b1,
                                            float* __restrict__ z1) {
  __shared__ float sp[512];
  const int g = blockIdx.x;
  const float cntg = (float)(gstart[g + 1] - gstart[g]);
  for (int i = threadIdx.x; i < 512; i += 128) {
    int t = i >> 7, ch = i & 127;
    sp[i] = fmaf(bnscL[t * 256 + ch], S[(size_t)g * 512 + i], cntg * bnscL[t * 256 + 128 + ch]);
  }
  __syncthreads();
  const int c = threadIdx.x;
  float acc = b1[c];
  for (int j = 0; j < 512; ++j) acc = fmaf(sp[j], W1[j * 128 + c], acc);
  z1[(size_t)g * 128 + c] = acc;
}

__global__ __launch_bounds__(128) void k_zstat(const float* __restrict__ z1,
                                               const float* __restrict__ g1,
                                               const float* __restrict__ bt1,
                                               float* __restrict__ zsc) {
  const int c = threadIdx.x;
  float s = 0.f, q = 0.f;
  for (int g = 0; g < GG; ++g) {
    float v = z1[g * 128 + c];
    s += v;
    q = fmaf(v, v, q);
  }
  float mu = s * (1.0f / GG);
  float var = q * (1.0f / GG) - mu * mu;
  float inv = rsqrtf(var + EPSF);
  float sc = g1[c] * inv;
  zsc[c] = sc;
  zsc[128 + c] = bt1[c] - mu * sc;
}

__global__ __launch_bounds__(128) void k_out(const float* __restrict__ z1,
                                             const float* __restrict__ zsc,
                                             const float* __restrict__ W2,
                                             const float* __restrict__ b2,
                                             float* __restrict__ out) {
  __shared__ float zr[128];
  const int g = blockIdx.x;
  const int c = threadIdx.x;
  zr[c] = fmaxf(fmaf(z1[(size_t)g * 128 + c], zsc[c], zsc[128 + c]), 0.f);
  __syncthreads();
  if (c < OUTC) {
    float acc = b2[c];
    for (int k = 0; k < 128; ++k) acc = fmaf(zr[k], W2[k * OUTC + c], acc);
    out[(size_t)g * OUTC + c] = acc;
  }
}

// ---------- launch ----------

extern "C" void kernel_launch(void* const* d_in, const int* in_sizes, int n_in,
                              void* d_out, int out_size, void* d_ws, size_t ws_size,
                              hipStream_t stream) {
  const float* x      = (const float*)d_in[0];
  const int*   ei     = (const int*)d_in[1];
  const int*   batch  = (const int*)d_in[2];
  const float* Ws     = (const float*)d_in[3];
  const float* bs     = (const float*)d_in[4];
  const float* gammas = (const float*)d_in[5];
  const float* betas  = (const float*)d_in[6];
  const float* W1     = (const float*)d_in[7];
  const float* b1     = (const float*)d_in[8];
  const float* g1     = (const float*)d_in[9];
  const float* bt1    = (const float*)d_in[10];
  const float* W2     = (const float*)d_in[11];
  const float* b2     = (const float*)d_in[12];
  float* out = (float*)d_out;

  char* ws = (char*)d_ws;
  size_t off = 0;
  auto alloc = [&](size_t bytes) -> void* {
    void* p = ws + off;
    off = (off + bytes + 255) & ~(size_t)255;
    return p;
  };
  // zero-initialized region (single memset)
  int*   deg    = (int*)alloc((size_t)NN * 4);
  int*   cnt    = (int*)alloc((size_t)NN * 4);
  float* bnbuf  = (float*)alloc((size_t)LL * 256 * 4);
  float* pooled = (float*)alloc((size_t)GG * 512 * 4);
  float* swsum  = (float*)alloc((size_t)NN * 4);
  float* zbase  = (float*)alloc(128 * 4);          // zeros: layer-0 base term
  size_t zero_bytes = off;
  // rest
  unsigned* Ar     = (unsigned*)alloc((size_t)NN * 64 * 4); // packed bf16 relu output
  unsigned* Ab     = (unsigned*)alloc((size_t)NN * 64 * 4); // packed bf16 layer-0 GEMM input
  unsigned* Bb     = (unsigned*)alloc((size_t)NN * 64 * 4); // packed bf16 H@W (gather src)
  int2*     ecw    = (int2*)alloc((size_t)EE * 8);
  float*    dinv   = (float*)alloc((size_t)NN * 4);
  int*      rowptr = (int*)alloc((size_t)(NN + 1) * 4);
  int*      bsum   = (int*)alloc((size_t)NSCB * 4);
  int*      gstart = (int*)alloc((size_t)(GG + 1) * 4);
  uint4*    Wf     = (uint4*)alloc((size_t)4096 * 16);      // MFMA W fragments (hi/lo), one layer
  float*    z1     = (float*)alloc((size_t)GG * FF * 4);
  float*    bnscL  = (float*)alloc((size_t)LL * 256 * 4);   // per-layer BN (sc, sh)
  float*    basebf = (float*)alloc(128 * 4);                // sh @ W_{t+1}
  float*    zsc    = (float*)alloc(256 * 4);
  (void)ws_size; (void)in_sizes; (void)n_in; (void)out_size;

  hipMemsetAsync(d_ws, 0, zero_bytes, stream);

  k_deg<<<(EE + 255) / 256, 256, 0, stream>>>(ei + EE, deg);
  k_dinv<<<(NN + 255) / 256, 256, 0, stream>>>(deg, dinv);
  k_bsum<<<NSCB, 256, 0, stream>>>(deg, bsum);
  k_rowptr<<<NSCB, 256, 0, stream>>>(deg, bsum, rowptr);
  k_fill<<<(EE + 255) / 256, 256, 0, stream>>>(ei, rowptr, cnt, dinv, ecw, swsum);
  k_bounds<<<(NN + 255) / 256, 256, 0, stream>>>(batch, gstart);
  k_cvt<<<(NN * 64 + 255) / 256, 256, 0, stream>>>(x, Ab);
  k_wcvt<<<16, 256, 0, stream>>>(Ws, nullptr, Wf);

  for (int t = 0; t < LL; ++t) {
    k_mm<<<(NN + 63) / 64, 256, 0, stream>>>(t == 0 ? Ab : Ar, Wf, Bb);
    k_agg<<<AGG_BLOCKS, 256, 0, stream>>>(Bb, rowptr, ecw, bs + t * FF,
                                          t == 0 ? zbase : basebf, swsum, batch,
                                          Ar, bnbuf + t * 256, pooled + t * FF);
    k_bnfin<<<1, 128, 0, stream>>>(bnbuf + t * 256, gammas + t * FF, betas + t * FF,
                                   bnscL + t * 256);
    if (t < LL - 1) {
      k_wcvt<<<16, 256, 0, stream>>>(Ws + (size_t)(t + 1) * 16384, bnscL + t * 256, Wf);
      k_base<<<1, 128, 0, stream>>>(Ws + (size_t)(t + 1) * 16384, bnscL + t * 256, basebf);
    }
  }

  k_z1<<<GG, 128, 0, stream>>>(pooled, bnscL, gstart, W1, b1, z1);
  k_zstat<<<1, 128, 0, stream>>>(z1, g1, bt1, zsc);
  k_out<<<GG, 128, 0, stream>>>(z1, zsc, W2, b2, out);
}

// Round 3
// 910.251 us; speedup vs baseline: 2.0845x; 2.0845x over previous
//
#include <hip/hip_runtime.h>

#define NN 100000
#define EE 1600000
#define FF 128
#define LL 4
#define GG 512
#define OUTC 10
#define EPSF 1e-5f
#define NSCB ((NN + 255) / 256)   // 391 scan blocks

// k_agg geometry: each wave owns NPW contiguous nodes => contiguous CSR edge range
#define NPW 8
#define AGG_WAVES ((NN + NPW - 1) / NPW)
#define AGG_BLOCKS ((AGG_WAVES + 3) / 4)

typedef __attribute__((ext_vector_type(8))) short short8;
typedef __attribute__((ext_vector_type(4))) float f32x4;

__device__ inline unsigned bf16rne(float f) {
  unsigned u = __float_as_uint(f);
  return (u + 0x7fffu + ((u >> 16) & 1u)) >> 16;
}
__device__ inline unsigned packbf(float lo, float hi) {
  return bf16rne(lo) | (bf16rne(hi) << 16);
}
__device__ inline float bflo(unsigned u) { return __uint_as_float(u << 16); }
__device__ inline float bfhi(unsigned u) { return __uint_as_float(u & 0xffff0000u); }

// ---------- graph setup ----------

__global__ __launch_bounds__(256) void k_deg(const int* __restrict__ col, int* __restrict__ deg) {
  int e = blockIdx.x * 256 + threadIdx.x;
  if (e < EE) atomicAdd(&deg[col[e]], 1);
}

// per-block degree sums (391 blocks x 256) + dinv (fused elementwise)
__global__ __launch_bounds__(256) void k_bsum(const int* __restrict__ deg,
                                              int* __restrict__ bsum,
                                              float* __restrict__ dinv) {
  int i = blockIdx.x * 256 + threadIdx.x;
  int v = (i < NN) ? deg[i] : 0;
  if (i < NN) dinv[i] = v > 0 ? rsqrtf((float)v) : 0.0f;
#pragma unroll
  for (int off = 32; off > 0; off >>= 1) v += __shfl_down(v, off, 64);
  __shared__ int ws[4];
  if ((threadIdx.x & 63) == 0) ws[threadIdx.x >> 6] = v;
  __syncthreads();
  if (threadIdx.x == 0) bsum[blockIdx.x] = ws[0] + ws[1] + ws[2] + ws[3];
}

// each block: scan all block sums in LDS (redundant), local scan of its 256 degs,
// write exclusive rowptr. rowptr[NN] = EE (constant).
__global__ __launch_bounds__(256) void k_rowptr(const int* __restrict__ deg,
                                                const int* __restrict__ bsum,
                                                int* __restrict__ rowptr) {
  __shared__ int sb[512];
  __shared__ int sd[256];
  const int t = threadIdx.x;
  sb[t]       = (t < NSCB) ? bsum[t] : 0;
  sb[t + 256] = (t + 256 < NSCB) ? bsum[t + 256] : 0;
  __syncthreads();
#pragma unroll
  for (int off = 1; off < 512; off <<= 1) {
    int v0 = (t >= off) ? sb[t - off] : 0;
    int v1 = sb[t + 256 - off];
    __syncthreads();
    sb[t] += v0;
    sb[t + 256] += v1;
    __syncthreads();
  }
  const int bpre = (blockIdx.x == 0) ? 0 : sb[blockIdx.x - 1];
  const int i = blockIdx.x * 256 + t;
  const int d = (i < NN) ? deg[i] : 0;
  sd[t] = d;
  __syncthreads();
#pragma unroll
  for (int off = 1; off < 256; off <<= 1) {
    int v = (t >= off) ? sd[t - off] : 0;
    __syncthreads();
    sd[t] += v;
    __syncthreads();
  }
  if (i < NN) rowptr[i] = bpre + sd[t] - d;
  if (blockIdx.x == 0 && t == 0) rowptr[NN] = EE;
}

// build CSR: one interleaved (src, weight) int2 store per edge
__global__ __launch_bounds__(256) void k_fill(const int* __restrict__ ei,
                                              const int* __restrict__ rowptr,
                                              int* __restrict__ cnt,
                                              const float* __restrict__ dinv,
                                              int2* __restrict__ ecw) {
  int e = blockIdx.x * 256 + threadIdx.x;
  if (e >= EE) return;
  int r = ei[e];
  int cl = ei[EE + e];
  int slot = rowptr[cl] + atomicAdd(&cnt[cl], 1);
  ecw[slot] = make_int2(r, __float_as_int(dinv[r] * dinv[cl]));
}

// ---------- bf16 conversions ----------

// x[N,128] fp32 -> Ab packed bf16 pairs; fused: gstart bounds from sorted batch
__global__ __launch_bounds__(256) void k_cvt(const float* __restrict__ x,
                                             const int* __restrict__ batch,
                                             unsigned* __restrict__ Ab,
                                             int* __restrict__ gstart) {
  int i = blockIdx.x * 256 + threadIdx.x;
  if (i < NN * 64) {
    float2 v = *(const float2*)(x + (size_t)i * 2);
    Ab[i] = packbf(v.x, v.y);
  }
  if (i < NN) {
    int b = batch[i];
    if (i == 0) {
      for (int g = 0; g <= b; ++g) gstart[g] = 0;
    } else {
      int bp = batch[i - 1];
      for (int g = bp + 1; g <= b; ++g) gstart[g] = i;
    }
    if (i == NN - 1) {
      for (int g = b + 1; g <= GG; ++g) gstart[g] = NN;
    }
  }
}

// W[128,128] fp32 -> MFMA B-fragments, hi/lo bf16 split (layer-0, no scale).
// frag index: ((kc*8 + ct)*2 + which), 64 lanes * 16B.
__global__ __launch_bounds__(256) void k_wcvt(const float* __restrict__ W,
                                              uint4* __restrict__ Wf) {
  int tid = blockIdx.x * 256 + threadIdx.x;   // 0..4095
  int lane = tid & 63;
  int which = (tid >> 6) & 1;
  int ct = (tid >> 7) & 7;
  int kc = tid >> 10;
  int n = ct * 16 + (lane & 15);
  int k0 = kc * 32 + (lane >> 4) * 8;
  unsigned h[8];
#pragma unroll
  for (int j = 0; j < 8; ++j) {
    float w = W[(k0 + j) * 128 + n];
    unsigned hb = bf16rne(w);
    if (which == 0) {
      h[j] = hb;
    } else {
      float hf = __uint_as_float(hb << 16);
      h[j] = bf16rne(w - hf);
    }
  }
  uint4 o;
  o.x = h[0] | (h[1] << 16);
  o.y = h[2] | (h[3] << 16);
  o.z = h[4] | (h[5] << 16);
  o.w = h[6] | (h[7] << 16);
  Wf[tid] = o;
}

// Fused per-layer epilogue: every block computes BN affine (sc, sh) from bnbuf
// (redundant, 512 B); block 0 stores it to bnsc. If gridDim>1 (not last layer):
// blocks 0..15 emit next layer's scaled W fragments, block 16 computes
// base[c] = sum_k sh[k]*Wnext[k,c].
__global__ __launch_bounds__(256) void k_post(const float* __restrict__ bnbuf,
                                              const float* __restrict__ gamma,
                                              const float* __restrict__ beta,
                                              float* __restrict__ bnsc,
                                              const float* __restrict__ Wnext,
                                              uint4* __restrict__ Wf,
                                              float* __restrict__ baseo) {
  __shared__ float ssc[256];
  const int t = threadIdx.x;
  if (t < 128) {
    float mu = bnbuf[t] * (1.0f / NN);
    float var = bnbuf[128 + t] * (1.0f / NN) - mu * mu;
    float inv = rsqrtf(var + EPSF);
    float sc = gamma[t] * inv;
    float sh = beta[t] - mu * sc;
    ssc[t] = sc;
    ssc[128 + t] = sh;
    if (blockIdx.x == 0) {
      bnsc[t] = sc;
      bnsc[128 + t] = sh;
    }
  }
  __syncthreads();
  if (gridDim.x == 1) return;   // last layer: stats only
  if (blockIdx.x < 16) {
    int tid = blockIdx.x * 256 + t;
    int lane = tid & 63;
    int which = (tid >> 6) & 1;
    int ct = (tid >> 7) & 7;
    int kc = tid >> 10;
    int n = ct * 16 + (lane & 15);
    int k0 = kc * 32 + (lane >> 4) * 8;
    unsigned h[8];
#pragma unroll
    for (int j = 0; j < 8; ++j) {
      float w = Wnext[(k0 + j) * 128 + n] * ssc[k0 + j];
      unsigned hb = bf16rne(w);
      if (which == 0) {
        h[j] = hb;
      } else {
        float hf = __uint_as_float(hb << 16);
        h[j] = bf16rne(w - hf);
      }
    }
    uint4 o;
    o.x = h[0] | (h[1] << 16);
    o.y = h[2] | (h[3] << 16);
    o.z = h[4] | (h[5] << 16);
    o.w = h[6] | (h[7] << 16);
    Wf[tid] = o;
  } else if (t < 128) {
    float acc = 0.f;
    for (int k = 0; k < 128; ++k) acc = fmaf(ssc[128 + k], Wnext[k * 128 + t], acc);
    baseo[t] = acc;
  }
}

// ---------- per-layer GEMM via MFMA: Bb[N,128](packed bf16) = Ab @ (Whi+Wlo) ----------
__global__ __launch_bounds__(256) void k_mm(const unsigned* __restrict__ Ab,
                                            const uint4* __restrict__ Wf,
                                            unsigned* __restrict__ Bb) {
  const int lane = threadIdx.x & 63;
  const int w = threadIdx.x >> 6;
  const int quad = lane >> 4;
  const int m = lane & 15;
  const int rowbase = blockIdx.x * 64 + w * 16;
  const int arow = min(rowbase + m, NN - 1);
  const uint4* A4 = (const uint4*)Ab;
  f32x4 acc[8];
#pragma unroll
  for (int ct = 0; ct < 8; ++ct) acc[ct] = (f32x4){0.f, 0.f, 0.f, 0.f};
#pragma unroll
  for (int kc = 0; kc < 4; ++kc) {
    uint4 av = A4[arow * 16 + kc * 4 + quad];
    short8 af = *(short8*)&av;
#pragma unroll
    for (int ct = 0; ct < 8; ++ct) {
      uint4 bh = Wf[((kc * 8 + ct) * 2 + 0) * 64 + lane];
      uint4 bl = Wf[((kc * 8 + ct) * 2 + 1) * 64 + lane];
      acc[ct] = __builtin_amdgcn_mfma_f32_16x16x32_bf16(af, *(short8*)&bh, acc[ct], 0, 0, 0);
      acc[ct] = __builtin_amdgcn_mfma_f32_16x16x32_bf16(af, *(short8*)&bl, acc[ct], 0, 0, 0);
    }
  }
#pragma unroll
  for (int ct = 0; ct < 8; ++ct) {
#pragma unroll
    for (int r = 0; r < 4; ++r) {
      float v = acc[ct][r];
      float vo = __shfl_xor(v, 1);
      int row = rowbase + quad * 4 + r;
      if ((lane & 1) == 0 && row < NN) {
        Bb[row * 64 + ct * 8 + (m >> 1)] = packbf(v, vo);
      }
    }
  }
}

// ---------- aggregation ----------
// Ar[n] = packbf(relu(sum_e w*B[src] + (sum_e w)*base + bias)), BN partial sums,
// and per-graph pooled raw sums (pooling of BN output is affine -> applied in k_z1).
// Each wave owns NPW contiguous nodes => one contiguous CSR edge range.
// Edge-descriptor LDS reads are double-buffered (ewA/ewB) so the next group's
// descriptors load during the current group's gather/FMA phase.
__global__ __launch_bounds__(256) void k_agg(const unsigned* __restrict__ Bb,
                                             const int* __restrict__ rowptr,
                                             const int2* __restrict__ ecw,
                                             const float* __restrict__ bias,
                                             const float* __restrict__ base,
                                             const int* __restrict__ batch,
                                             unsigned* __restrict__ Ar,
                                             float* __restrict__ bnbuf,
                                             float* __restrict__ pooledt) {
  const int lane = threadIdx.x & 63;
  const int wave = threadIdx.x >> 6;
  const int c = lane * 2;
  const int gwave = blockIdx.x * 4 + wave;
  const int n0 = gwave * NPW;
  const float2 bv = *(const float2*)(bias + c);
  const float2 basev = *(const float2*)(base + c);
  float s0 = 0.f, s1 = 0.f, q0 = 0.f, q1 = 0.f;
  __shared__ int srp[4][NPW + 1];
  __shared__ int2 sstage[4][64];
  if (n0 < NN) {
    const int nn = min(NPW, NN - n0);
    if (lane <= nn) srp[wave][lane] = rowptr[n0 + lane];
    int bsp = (lane < nn) ? batch[n0 + lane] : 0;
    float ax0 = 0.f, ax1 = 0.f, ay0 = 0.f, ay1 = 0.f, sw = 0.f;
    float px = 0.f, py = 0.f;
    int gprev = -1;
    auto finalize = [&](int node) {
      float rx = fmaxf(fmaf(sw, basev.x, ax0 + ax1) + bv.x, 0.f);
      float ry = fmaxf(fmaf(sw, basev.y, ay0 + ay1) + bv.y, 0.f);
      Ar[(size_t)(n0 + node) * 64 + lane] = packbf(rx, ry);
      s0 += rx; s1 += ry;
      q0 = fmaf(rx, rx, q0); q1 = fmaf(ry, ry, q1);
      int g = __shfl(bsp, node);
      if (g != gprev) {
        if (gprev >= 0) {
          atomicAdd(&pooledt[(size_t)gprev * 512 + c], px);
          atomicAdd(&pooledt[(size_t)gprev * 512 + c + 1], py);
        }
        gprev = g; px = 0.f; py = 0.f;
      }
      px += rx; py += ry;
      ax0 = 0.f; ax1 = 0.f; ay0 = 0.f; ay1 = 0.f; sw = 0.f;
    };
    const int beg = __builtin_amdgcn_readfirstlane(srp[wave][0]);
    const int endall = __builtin_amdgcn_readfirstlane(srp[wave][nn]);
    int cn = 0;
    // leading (and possibly all) empty nodes
    while (cn < nn && __builtin_amdgcn_readfirstlane(srp[wave][cn + 1]) == beg) {
      finalize(cn);
      ++cn;
    }
    int nend = (cn < nn) ? __builtin_amdgcn_readfirstlane(srp[wave][cn + 1]) : 0x7fffffff;
    int2 stage = (beg + lane < endall) ? ecw[beg + lane] : make_int2(0, 0);
    for (int base_e = beg; base_e < endall; base_e += 64) {
      sstage[wave][lane] = stage;     // current chunk -> LDS (same-wave, in-order)
      const int nb = base_e + 64;
      if (nb < endall) {              // prefetch next chunk off critical path
        stage = (nb + lane < endall) ? ecw[nb + lane] : make_int2(0, 0);
      }
      int2 ewA[16], ewB[16];
#pragma unroll
      for (int j = 0; j < 16; ++j) ewA[j] = sstage[wave][j];

#define PROC(G, CUR, NXT, PREF)                                               \
  if (base_e + (G) * 16 < endall) {                                           \
    if (PREF) {                                                               \
      _Pragma("unroll")                                                       \
      for (int j = 0; j < 16; ++j) NXT[j] = sstage[wave][((G) + 1) * 16 + j]; \
    }                                                                         \
    unsigned us[16];                                                          \
    _Pragma("unroll")                                                         \
    for (int j = 0; j < 16; ++j) {                                            \
      const int sj = __builtin_amdgcn_readfirstlane(CUR[j].x);                \
      us[j] = Bb[((size_t)(unsigned)sj << 6) + (unsigned)lane];               \
    }                                                                         \
    _Pragma("unroll")                                                         \
    for (int j = 0; j < 16; ++j) {                                            \
      const float wj = __int_as_float(CUR[j].y);                              \
      sw += wj;                                                               \
      if (j & 1) {                                                            \
        ax1 = fmaf(wj, bflo(us[j]), ax1);                                     \
        ay1 = fmaf(wj, bfhi(us[j]), ay1);                                     \
      } else {                                                                \
        ax0 = fmaf(wj, bflo(us[j]), ax0);                                     \
        ay0 = fmaf(wj, bfhi(us[j]), ay0);                                     \
      }                                                                       \
      const int e1 = base_e + (G) * 16 + j + 1;                               \
      if (e1 == nend) {                                                       \
        finalize(cn); ++cn;                                                   \
        nend = (cn < nn) ? __builtin_amdgcn_readfirstlane(srp[wave][cn + 1])  \
                         : 0x7fffffff;                                        \
        while (cn < nn && nend == e1) {                                       \
          finalize(cn); ++cn;                                                 \
          nend = (cn < nn)                                                    \
                     ? __builtin_amdgcn_readfirstlane(srp[wave][cn + 1])      \
                     : 0x7fffffff;                                            \
        }                                                                     \
      }                                                                       \
    }                                                                         \
  }

      PROC(0, ewA, ewB, true)
      PROC(1, ewB, ewA, true)
      PROC(2, ewA, ewB, true)
      PROC(3, ewB, ewA, false)
#undef PROC
    }
    if (gprev >= 0) {
      atomicAdd(&pooledt[(size_t)gprev * 512 + c], px);
      atomicAdd(&pooledt[(size_t)gprev * 512 + c + 1], py);
    }
  }
  __shared__ float sred[4][256];
  sred[wave][c] = s0;
  sred[wave][c + 1] = s1;
  sred[wave][128 + c] = q0;
  sred[wave][128 + c + 1] = q1;
  __syncthreads();
  const int t = threadIdx.x;
  float tot = sred[0][t] + sred[1][t] + sred[2][t] + sred[3][t];
  atomicAdd(&bnbuf[t], tot);
}

// ---------- head ----------

// z1 = (affine-pooled) @ W1 + b1 where pooled_gc = sc_c*S_gc + cnt_g*sh_c
__global__ __launch_bounds__(128) void k_z1(const float* __restrict__ S,
                                            const float* __restrict__ bnscL,
                                            const int* __restrict__ gstart,
                                            const float* __restrict__ W1,
                                            const float* __restrict__ b1,
                                            float* __restrict__ z1) {
  __shared__ float sp[512];
  const int g = blockIdx.x;
  const float cntg = (float)(gstart[g + 1] - gstart[g]);
  for (int i = threadIdx.x; i < 512; i += 128) {
    int t = i >> 7, ch = i & 127;
    sp[i] = fmaf(bnscL[t * 256 + ch], S[(size_t)g * 512 + i], cntg * bnscL[t * 256 + 128 + ch]);
  }
  __syncthreads();
  const int c = threadIdx.x;
  float acc = b1[c];
  for (int j = 0; j < 512; ++j) acc = fmaf(sp[j], W1[j * 128 + c], acc);
  z1[(size_t)g * 128 + c] = acc;
}

__global__ __launch_bounds__(128) void k_zstat(const float* __restrict__ z1,
                                               const float* __restrict__ g1,
                                               const float* __restrict__ bt1,
                                               float* __restrict__ zsc) {
  const int c = threadIdx.x;
  float s = 0.f, q = 0.f;
  for (int g = 0; g < GG; ++g) {
    float v = z1[g * 128 + c];
    s += v;
    q = fmaf(v, v, q);
  }
  float mu = s * (1.0f / GG);
  float var = q * (1.0f / GG) - mu * mu;
  float inv = rsqrtf(var + EPSF);
  float sc = g1[c] * inv;
  zsc[c] = sc;
  zsc[128 + c] = bt1[c] - mu * sc;
}

__global__ __launch_bounds__(128) void k_out(const float* __restrict__ z1,
                                             const float* __restrict__ zsc,
                                             const float* __restrict__ W2,
                                             const float* __restrict__ b2,
                                             float* __restrict__ out) {
  __shared__ float zr[128];
  const int g = blockIdx.x;
  const int c = threadIdx.x;
  zr[c] = fmaxf(fmaf(z1[(size_t)g * 128 + c], zsc[c], zsc[128 + c]), 0.f);
  __syncthreads();
  if (c < OUTC) {
    float acc = b2[c];
    for (int k = 0; k < 128; ++k) acc = fmaf(zr[k], W2[k * OUTC + c], acc);
    out[(size_t)g * OUTC + c] = acc;
  }
}

// ---------- launch ----------

extern "C" void kernel_launch(void* const* d_in, const int* in_sizes, int n_in,
                              void* d_out, int out_size, void* d_ws, size_t ws_size,
                              hipStream_t stream) {
  const float* x      = (const float*)d_in[0];
  const int*   ei     = (const int*)d_in[1];
  const int*   batch  = (const int*)d_in[2];
  const float* Ws     = (const float*)d_in[3];
  const float* bs     = (const float*)d_in[4];
  const float* gammas = (const float*)d_in[5];
  const float* betas  = (const float*)d_in[6];
  const float* W1     = (const float*)d_in[7];
  const float* b1     = (const float*)d_in[8];
  const float* g1     = (const float*)d_in[9];
  const float* bt1    = (const float*)d_in[10];
  const float* W2     = (const float*)d_in[11];
  const float* b2     = (const float*)d_in[12];
  float* out = (float*)d_out;

  char* ws = (char*)d_ws;
  size_t off = 0;
  auto alloc = [&](size_t bytes) -> void* {
    void* p = ws + off;
    off = (off + bytes + 255) & ~(size_t)255;
    return p;
  };
  // zero-initialized region (single memset)
  int*   deg    = (int*)alloc((size_t)NN * 4);
  int*   cnt    = (int*)alloc((size_t)NN * 4);
  float* bnbuf  = (float*)alloc((size_t)LL * 256 * 4);
  float* pooled = (float*)alloc((size_t)GG * 512 * 4);
  float* zbase  = (float*)alloc(128 * 4);          // zeros: layer-0 base term
  size_t zero_bytes = off;
  // rest
  unsigned* Ar     = (unsigned*)alloc((size_t)NN * 64 * 4); // packed bf16 relu output
  unsigned* Ab     = (unsigned*)alloc((size_t)NN * 64 * 4); // packed bf16 layer-0 GEMM input
  unsigned* Bb     = (unsigned*)alloc((size_t)NN * 64 * 4); // packed bf16 H@W (gather src)
  int2*     ecw    = (int2*)alloc((size_t)EE * 8);
  float*    dinv   = (float*)alloc((size_t)NN * 4);
  int*      rowptr = (int*)alloc((size_t)(NN + 1) * 4);
  int*      bsum   = (int*)alloc((size_t)NSCB * 4);
  int*      gstart = (int*)alloc((size_t)(GG + 1) * 4);
  uint4*    Wf     = (uint4*)alloc((size_t)4096 * 16);      // MFMA W fragments (hi/lo), one layer
  float*    z1     = (float*)alloc((size_t)GG * FF * 4);
  float*    bnscL  = (float*)alloc((size_t)LL * 256 * 4);   // per-layer BN (sc, sh)
  float*    basebf = (float*)alloc(128 * 4);                // sh @ W_{t+1}
  float*    zsc    = (float*)alloc(256 * 4);
  (void)ws_size; (void)in_sizes; (void)n_in; (void)out_size;

  hipMemsetAsync(d_ws, 0, zero_bytes, stream);

  k_deg<<<(EE + 255) / 256, 256, 0, stream>>>(ei + EE, deg);
  k_bsum<<<NSCB, 256, 0, stream>>>(deg, bsum, dinv);
  k_rowptr<<<NSCB, 256, 0, stream>>>(deg, bsum, rowptr);
  k_fill<<<(EE + 255) / 256, 256, 0, stream>>>(ei, rowptr, cnt, dinv, ecw);
  k_cvt<<<(NN * 64 + 255) / 256, 256, 0, stream>>>(x, batch, Ab, gstart);
  k_wcvt<<<16, 256, 0, stream>>>(Ws, Wf);

  for (int t = 0; t < LL; ++t) {
    k_mm<<<(NN + 63) / 64, 256, 0, stream>>>(t == 0 ? Ab : Ar, Wf, Bb);
    k_agg<<<AGG_BLOCKS, 256, 0, stream>>>(Bb, rowptr, ecw, bs + t * FF,
                                          t == 0 ? zbase : basebf, batch,
                                          Ar, bnbuf + t * 256, pooled + t * FF);
    if (t < LL - 1) {
      k_post<<<17, 256, 0, stream>>>(bnbuf + t * 256, gammas + t * FF, betas + t * FF,
                                     bnscL + t * 256, Ws + (size_t)(t + 1) * 16384,
                                     Wf, basebf);
    } else {
      k_post<<<1, 256, 0, stream>>>(bnbuf + t * 256, gammas + t * FF, betas + t * FF,
                                    bnscL + t * 256, nullptr, nullptr, nullptr);
    }
  }

  k_z1<<<GG, 128, 0, stream>>>(pooled, bnscL, gstart, W1, b1, z1);
  k_zstat<<<1, 128, 0, stream>>>(z1, g1, bt1, zsc);
  k_out<<<GG, 128, 0, stream>>>(z1, zsc, W2, b2, out);
}

// Round 4
// 781.294 us; speedup vs baseline: 2.4286x; 1.1651x over previous
//
#include <hip/hip_runtime.h>

#define NN 100000
#define EE 1600000
#define FF 128
#define LL 4
#define GG 512
#define OUTC 10
#define EPSF 1e-5f
#define NSCB ((NN + 255) / 256)   // 391 scan blocks

// k_agg geometry: each wave owns NPW contiguous nodes => contiguous CSR edge range
#define NPW 16
#define AGG_WAVES ((NN + NPW - 1) / NPW)
#define AGG_BLOCKS ((AGG_WAVES + 3) / 4)

typedef __attribute__((ext_vector_type(8))) short short8;
typedef __attribute__((ext_vector_type(4))) float f32x4;

__device__ inline unsigned bf16rne(float f) {
  unsigned u = __float_as_uint(f);
  return (u + 0x7fffu + ((u >> 16) & 1u)) >> 16;
}
__device__ inline unsigned packbf(float lo, float hi) {
  return bf16rne(lo) | (bf16rne(hi) << 16);
}
__device__ inline float bflo(unsigned u) { return __uint_as_float(u << 16); }
__device__ inline float bfhi(unsigned u) { return __uint_as_float(u & 0xffff0000u); }

// ---------- graph setup ----------

__global__ __launch_bounds__(256) void k_deg(const int* __restrict__ col, int* __restrict__ deg) {
  int e = blockIdx.x * 256 + threadIdx.x;
  if (e < EE) atomicAdd(&deg[col[e]], 1);
}

// per-block degree sums (391 blocks x 256) + dinv (fused elementwise)
__global__ __launch_bounds__(256) void k_bsum(const int* __restrict__ deg,
                                              int* __restrict__ bsum,
                                              float* __restrict__ dinv) {
  int i = blockIdx.x * 256 + threadIdx.x;
  int v = (i < NN) ? deg[i] : 0;
  if (i < NN) dinv[i] = v > 0 ? rsqrtf((float)v) : 0.0f;
#pragma unroll
  for (int off = 32; off > 0; off >>= 1) v += __shfl_down(v, off, 64);
  __shared__ int ws[4];
  if ((threadIdx.x & 63) == 0) ws[threadIdx.x >> 6] = v;
  __syncthreads();
  if (threadIdx.x == 0) bsum[blockIdx.x] = ws[0] + ws[1] + ws[2] + ws[3];
}

// each block: scan all block sums in LDS (redundant), local scan of its 256 degs,
// write exclusive rowptr. rowptr[NN] = EE (constant).
__global__ __launch_bounds__(256) void k_rowptr(const int* __restrict__ deg,
                                                const int* __restrict__ bsum,
                                                int* __restrict__ rowptr) {
  __shared__ int sb[512];
  __shared__ int sd[256];
  const int t = threadIdx.x;
  sb[t]       = (t < NSCB) ? bsum[t] : 0;
  sb[t + 256] = (t + 256 < NSCB) ? bsum[t + 256] : 0;
  __syncthreads();
#pragma unroll
  for (int off = 1; off < 512; off <<= 1) {
    int v0 = (t >= off) ? sb[t - off] : 0;
    int v1 = sb[t + 256 - off];
    __syncthreads();
    sb[t] += v0;
    sb[t + 256] += v1;
    __syncthreads();
  }
  const int bpre = (blockIdx.x == 0) ? 0 : sb[blockIdx.x - 1];
  const int i = blockIdx.x * 256 + t;
  const int d = (i < NN) ? deg[i] : 0;
  sd[t] = d;
  __syncthreads();
#pragma unroll
  for (int off = 1; off < 256; off <<= 1) {
    int v = (t >= off) ? sd[t - off] : 0;
    __syncthreads();
    sd[t] += v;
    __syncthreads();
  }
  if (i < NN) rowptr[i] = bpre + sd[t] - d;
  if (blockIdx.x == 0 && t == 0) rowptr[NN] = EE;
}

// build CSR: one interleaved (src, weight) int2 store per edge
__global__ __launch_bounds__(256) void k_fill(const int* __restrict__ ei,
                                              const int* __restrict__ rowptr,
                                              int* __restrict__ cnt,
                                              const float* __restrict__ dinv,
                                              int2* __restrict__ ecw) {
  int e = blockIdx.x * 256 + threadIdx.x;
  if (e >= EE) return;
  int r = ei[e];
  int cl = ei[EE + e];
  int slot = rowptr[cl] + atomicAdd(&cnt[cl], 1);
  ecw[slot] = make_int2(r, __float_as_int(dinv[r] * dinv[cl]));
}

// ---------- bf16 conversions ----------

// x[N,128] fp32 -> Ab packed bf16 pairs; fused: gstart bounds from sorted batch
__global__ __launch_bounds__(256) void k_cvt(const float* __restrict__ x,
                                             const int* __restrict__ batch,
                                             unsigned* __restrict__ Ab,
                                             int* __restrict__ gstart) {
  int i = blockIdx.x * 256 + threadIdx.x;
  if (i < NN * 64) {
    float2 v = *(const float2*)(x + (size_t)i * 2);
    Ab[i] = packbf(v.x, v.y);
  }
  if (i < NN) {
    int b = batch[i];
    if (i == 0) {
      for (int g = 0; g <= b; ++g) gstart[g] = 0;
    } else {
      int bp = batch[i - 1];
      for (int g = bp + 1; g <= b; ++g) gstart[g] = i;
    }
    if (i == NN - 1) {
      for (int g = b + 1; g <= GG; ++g) gstart[g] = NN;
    }
  }
}

// W[128,128] fp32 -> MFMA B-fragments, hi/lo bf16 split (layer-0, no scale).
// frag index: ((kc*8 + ct)*2 + which), 64 lanes * 16B.
__global__ __launch_bounds__(256) void k_wcvt(const float* __restrict__ W,
                                              uint4* __restrict__ Wf) {
  int tid = blockIdx.x * 256 + threadIdx.x;   // 0..4095
  int lane = tid & 63;
  int which = (tid >> 6) & 1;
  int ct = (tid >> 7) & 7;
  int kc = tid >> 10;
  int n = ct * 16 + (lane & 15);
  int k0 = kc * 32 + (lane >> 4) * 8;
  unsigned h[8];
#pragma unroll
  for (int j = 0; j < 8; ++j) {
    float w = W[(k0 + j) * 128 + n];
    unsigned hb = bf16rne(w);
    if (which == 0) {
      h[j] = hb;
    } else {
      float hf = __uint_as_float(hb << 16);
      h[j] = bf16rne(w - hf);
    }
  }
  uint4 o;
  o.x = h[0] | (h[1] << 16);
  o.y = h[2] | (h[3] << 16);
  o.z = h[4] | (h[5] << 16);
  o.w = h[6] | (h[7] << 16);
  Wf[tid] = o;
}

// Fused per-layer epilogue: every block computes BN affine (sc, sh) from bnbuf
// (redundant, 512 B); block 0 stores it to bnsc. If gridDim>1 (not last layer):
// blocks 0..15 emit next layer's scaled W fragments, block 16 computes
// base[c] = sum_k sh[k]*Wnext[k,c].
__global__ __launch_bounds__(256) void k_post(const float* __restrict__ bnbuf,
                                              const float* __restrict__ gamma,
                                              const float* __restrict__ beta,
                                              float* __restrict__ bnsc,
                                              const float* __restrict__ Wnext,
                                              uint4* __restrict__ Wf,
                                              float* __restrict__ baseo) {
  __shared__ float ssc[256];
  const int t = threadIdx.x;
  if (t < 128) {
    float mu = bnbuf[t] * (1.0f / NN);
    float var = bnbuf[128 + t] * (1.0f / NN) - mu * mu;
    float inv = rsqrtf(var + EPSF);
    float sc = gamma[t] * inv;
    float sh = beta[t] - mu * sc;
    ssc[t] = sc;
    ssc[128 + t] = sh;
    if (blockIdx.x == 0) {
      bnsc[t] = sc;
      bnsc[128 + t] = sh;
    }
  }
  __syncthreads();
  if (gridDim.x == 1) return;   // last layer: stats only
  if (blockIdx.x < 16) {
    int tid = blockIdx.x * 256 + t;
    int lane = tid & 63;
    int which = (tid >> 6) & 1;
    int ct = (tid >> 7) & 7;
    int kc = tid >> 10;
    int n = ct * 16 + (lane & 15);
    int k0 = kc * 32 + (lane >> 4) * 8;
    unsigned h[8];
#pragma unroll
    for (int j = 0; j < 8; ++j) {
      float w = Wnext[(k0 + j) * 128 + n] * ssc[k0 + j];
      unsigned hb = bf16rne(w);
      if (which == 0) {
        h[j] = hb;
      } else {
        float hf = __uint_as_float(hb << 16);
        h[j] = bf16rne(w - hf);
      }
    }
    uint4 o;
    o.x = h[0] | (h[1] << 16);
    o.y = h[2] | (h[3] << 16);
    o.z = h[4] | (h[5] << 16);
    o.w = h[6] | (h[7] << 16);
    Wf[tid] = o;
  } else if (t < 128) {
    float acc = 0.f;
    for (int k = 0; k < 128; ++k) acc = fmaf(ssc[128 + k], Wnext[k * 128 + t], acc);
    baseo[t] = acc;
  }
}

// ---------- per-layer GEMM via MFMA: Bb[N,128](packed bf16) = Ab @ (Whi+Wlo) ----------
__global__ __launch_bounds__(256) void k_mm(const unsigned* __restrict__ Ab,
                                            const uint4* __restrict__ Wf,
                                            unsigned* __restrict__ Bb) {
  const int lane = threadIdx.x & 63;
  const int w = threadIdx.x >> 6;
  const int quad = lane >> 4;
  const int m = lane & 15;
  const int rowbase = blockIdx.x * 64 + w * 16;
  const int arow = min(rowbase + m, NN - 1);
  const uint4* A4 = (const uint4*)Ab;
  f32x4 acc[8];
#pragma unroll
  for (int ct = 0; ct < 8; ++ct) acc[ct] = (f32x4){0.f, 0.f, 0.f, 0.f};
#pragma unroll
  for (int kc = 0; kc < 4; ++kc) {
    uint4 av = A4[arow * 16 + kc * 4 + quad];
    short8 af = *(short8*)&av;
#pragma unroll
    for (int ct = 0; ct < 8; ++ct) {
      uint4 bh = Wf[((kc * 8 + ct) * 2 + 0) * 64 + lane];
      uint4 bl = Wf[((kc * 8 + ct) * 2 + 1) * 64 + lane];
      acc[ct] = __builtin_amdgcn_mfma_f32_16x16x32_bf16(af, *(short8*)&bh, acc[ct], 0, 0, 0);
      acc[ct] = __builtin_amdgcn_mfma_f32_16x16x32_bf16(af, *(short8*)&bl, acc[ct], 0, 0, 0);
    }
  }
#pragma unroll
  for (int ct = 0; ct < 8; ++ct) {
#pragma unroll
    for (int r = 0; r < 4; ++r) {
      float v = acc[ct][r];
      float vo = __shfl_xor(v, 1);
      int row = rowbase + quad * 4 + r;
      if ((lane & 1) == 0 && row < NN) {
        Bb[row * 64 + ct * 8 + (m >> 1)] = packbf(v, vo);
      }
    }
  }
}

// ---------- aggregation ----------
// Ar[n] = packbf(relu(sum_e w*B[src] + (sum_e w)*base + bias)), BN partial sums,
// and per-graph pooled raw sums (pooling of BN output is affine -> applied in k_z1).
// Each wave owns NPW contiguous nodes => one contiguous CSR edge range (round-1
// measured-best inner loop: single ew buffer, 16 gathers in flight per group).
__global__ __launch_bounds__(256) void k_agg(const unsigned* __restrict__ Bb,
                                             const int* __restrict__ rowptr,
                                             const int2* __restrict__ ecw,
                                             const float* __restrict__ bias,
                                             const float* __restrict__ base,
                                             const int* __restrict__ batch,
                                             unsigned* __restrict__ Ar,
                                             float* __restrict__ bnbuf,
                                             float* __restrict__ pooledt) {
  const int lane = threadIdx.x & 63;
  const int wave = threadIdx.x >> 6;
  const int c = lane * 2;
  const int gwave = blockIdx.x * 4 + wave;
  const int n0 = gwave * NPW;
  const float2 bv = *(const float2*)(bias + c);
  const float2 basev = *(const float2*)(base + c);
  float s0 = 0.f, s1 = 0.f, q0 = 0.f, q1 = 0.f;
  __shared__ int srp[4][NPW + 1];
  __shared__ int2 sstage[4][64];
  if (n0 < NN) {
    const int nn = min(NPW, NN - n0);
    if (lane <= nn) srp[wave][lane] = rowptr[n0 + lane];
    int bsp = (lane < nn) ? batch[n0 + lane] : 0;
    float ax0 = 0.f, ax1 = 0.f, ay0 = 0.f, ay1 = 0.f, sw = 0.f;
    float px = 0.f, py = 0.f;
    int gprev = -1;
    auto finalize = [&](int node) {
      float rx = fmaxf(fmaf(sw, basev.x, ax0 + ax1) + bv.x, 0.f);
      float ry = fmaxf(fmaf(sw, basev.y, ay0 + ay1) + bv.y, 0.f);
      Ar[(size_t)(n0 + node) * 64 + lane] = packbf(rx, ry);
      s0 += rx; s1 += ry;
      q0 = fmaf(rx, rx, q0); q1 = fmaf(ry, ry, q1);
      int g = __shfl(bsp, node);
      if (g != gprev) {
        if (gprev >= 0) {
          atomicAdd(&pooledt[(size_t)gprev * 512 + c], px);
          atomicAdd(&pooledt[(size_t)gprev * 512 + c + 1], py);
        }
        gprev = g; px = 0.f; py = 0.f;
      }
      px += rx; py += ry;
      ax0 = 0.f; ax1 = 0.f; ay0 = 0.f; ay1 = 0.f; sw = 0.f;
    };
    const int beg = __builtin_amdgcn_readfirstlane(srp[wave][0]);
    const int endall = __builtin_amdgcn_readfirstlane(srp[wave][nn]);
    int cn = 0;
    // leading (and possibly all) empty nodes
    while (cn < nn && __builtin_amdgcn_readfirstlane(srp[wave][cn + 1]) == beg) {
      finalize(cn);
      ++cn;
    }
    int nend = (cn < nn) ? __builtin_amdgcn_readfirstlane(srp[wave][cn + 1]) : 0x7fffffff;
    int2 stage = (beg + lane < endall) ? ecw[beg + lane] : make_int2(0, 0);
    for (int base_e = beg; base_e < endall; base_e += 64) {
      sstage[wave][lane] = stage;     // current chunk -> LDS (same-wave, in-order)
      const int nb = base_e + 64;
      if (nb < endall) {              // prefetch next chunk off critical path
        stage = (nb + lane < endall) ? ecw[nb + lane] : make_int2(0, 0);
      }
#pragma unroll
      for (int g = 0; g < 4; ++g) {
        if (base_e + g * 16 < endall) {   // wave-uniform (SGPR) branch
          int2 ew[16]; unsigned us[16];
#pragma unroll
          for (int j = 0; j < 16; ++j) ew[j] = sstage[wave][g * 16 + j];  // broadcast
#pragma unroll
          for (int j = 0; j < 16; ++j) {
            const int sj = __builtin_amdgcn_readfirstlane(ew[j].x);       // SGPR base
            us[j] = Bb[((size_t)(unsigned)sj << 6) + (unsigned)lane];
          }
#pragma unroll
          for (int j = 0; j < 16; ++j) {
            const float wj = __int_as_float(ew[j].y);   // 0 for padding lanes
            sw += wj;
            if (j & 1) {
              ax1 = fmaf(wj, bflo(us[j]), ax1);
              ay1 = fmaf(wj, bfhi(us[j]), ay1);
            } else {
              ax0 = fmaf(wj, bflo(us[j]), ax0);
              ay0 = fmaf(wj, bfhi(us[j]), ay0);
            }
            const int e1 = base_e + g * 16 + j + 1;     // scalar
            if (e1 == nend) {                           // node boundary (SGPR cmp)
              finalize(cn);
              ++cn;
              nend = (cn < nn) ? __builtin_amdgcn_readfirstlane(srp[wave][cn + 1]) : 0x7fffffff;
              while (cn < nn && nend == e1) {           // empty nodes inside span
                finalize(cn);
                ++cn;
                nend = (cn < nn) ? __builtin_amdgcn_readfirstlane(srp[wave][cn + 1]) : 0x7fffffff;
              }
            }
          }
        }
      }
    }
    if (gprev >= 0) {
      atomicAdd(&pooledt[(size_t)gprev * 512 + c], px);
      atomicAdd(&pooledt[(size_t)gprev * 512 + c + 1], py);
    }
  }
  __shared__ float sred[4][256];
  sred[wave][c] = s0;
  sred[wave][c + 1] = s1;
  sred[wave][128 + c] = q0;
  sred[wave][128 + c + 1] = q1;
  __syncthreads();
  const int t = threadIdx.x;
  float tot = sred[0][t] + sred[1][t] + sred[2][t] + sred[3][t];
  atomicAdd(&bnbuf[t], tot);
}

// ---------- head ----------

// z1 = (affine-pooled) @ W1 + b1 where pooled_gc = sc_c*S_gc + cnt_g*sh_c
__global__ __launch_bounds__(128) void k_z1(const float* __restrict__ S,
                                            const float* __restrict__ bnscL,
                                            const int* __restrict__ gstart,
                                            const float* __restrict__ W1,
                                            const float* __restrict__ b1,
                                            float* __restrict__ z1) {
  __shared__ float sp[512];
  const int g = blockIdx.x;
  const float cntg = (float)(gstart[g + 1] - gstart[g]);
  for (int i = threadIdx.x; i < 512; i += 128) {
    int t = i >> 7, ch = i & 127;
    sp[i] = fmaf(bnscL[t * 256 + ch], S[(size_t)g * 512 + i], cntg * bnscL[t * 256 + 128 + ch]);
  }
  __syncthreads();
  const int c = threadIdx.x;
  float acc = b1[c];
  for (int j = 0; j < 512; ++j) acc = fmaf(sp[j], W1[j * 128 + c], acc);
  z1[(size_t)g * 128 + c] = acc;
}

// 1024 threads: 8 g-strided partial passes (coalesced in c) + LDS reduce
__global__ __launch_bounds__(1024) void k_zstat(const float* __restrict__ z1,
                                                const float* __restrict__ g1,
                                                const float* __restrict__ bt1,
                                                float* __restrict__ zsc) {
  const int t = threadIdx.x;
  const int c = t & 127;
  const int gr = t >> 7;   // 0..7
  float s = 0.f, q = 0.f;
  for (int g = gr; g < GG; g += 8) {
    float v = z1[(size_t)g * 128 + c];
    s += v;
    q = fmaf(v, v, q);
  }
  __shared__ float ss[8][128];
  __shared__ float sq[8][128];
  ss[gr][c] = s;
  sq[gr][c] = q;
  __syncthreads();
  if (t < 128) {
    float st = 0.f, qt = 0.f;
#pragma unroll
    for (int i = 0; i < 8; ++i) { st += ss[i][c]; qt += sq[i][c]; }
    float mu = st * (1.0f / GG);
    float var = qt * (1.0f / GG) - mu * mu;
    float inv = rsqrtf(var + EPSF);
    float sc = g1[c] * inv;
    zsc[c] = sc;
    zsc[128 + c] = bt1[c] - mu * sc;
  }
}

__global__ __launch_bounds__(128) void k_out(const float* __restrict__ z1,
                                             const float* __restrict__ zsc,
                                             const float* __restrict__ W2,
                                             const float* __restrict__ b2,
                                             float* __restrict__ out) {
  __shared__ float zr[128];
  const int g = blockIdx.x;
  const int c = threadIdx.x;
  zr[c] = fmaxf(fmaf(z1[(size_t)g * 128 + c], zsc[c], zsc[128 + c]), 0.f);
  __syncthreads();
  if (c < OUTC) {
    float acc = b2[c];
    for (int k = 0; k < 128; ++k) acc = fmaf(zr[k], W2[k * OUTC + c], acc);
    out[(size_t)g * OUTC + c] = acc;
  }
}

// ---------- launch ----------

extern "C" void kernel_launch(void* const* d_in, const int* in_sizes, int n_in,
                              void* d_out, int out_size, void* d_ws, size_t ws_size,
                              hipStream_t stream) {
  const float* x      = (const float*)d_in[0];
  const int*   ei     = (const int*)d_in[1];
  const int*   batch  = (const int*)d_in[2];
  const float* Ws     = (const float*)d_in[3];
  const float* bs     = (const float*)d_in[4];
  const float* gammas = (const float*)d_in[5];
  const float* betas  = (const float*)d_in[6];
  const float* W1     = (const float*)d_in[7];
  const float* b1     = (const float*)d_in[8];
  const float* g1     = (const float*)d_in[9];
  const float* bt1    = (const float*)d_in[10];
  const float* W2     = (const float*)d_in[11];
  const float* b2     = (const float*)d_in[12];
  float* out = (float*)d_out;

  char* ws = (char*)d_ws;
  size_t off = 0;
  auto alloc = [&](size_t bytes) -> void* {
    void* p = ws + off;
    off = (off + bytes + 255) & ~(size_t)255;
    return p;
  };
  // zero-initialized region (single memset)
  int*   deg    = (int*)alloc((size_t)NN * 4);
  int*   cnt    = (int*)alloc((size_t)NN * 4);
  float* bnbuf  = (float*)alloc((size_t)LL * 256 * 4);
  float* pooled = (float*)alloc((size_t)GG * 512 * 4);
  float* zbase  = (float*)alloc(128 * 4);          // zeros: layer-0 base term
  size_t zero_bytes = off;
  // rest
  unsigned* Ar     = (unsigned*)alloc((size_t)NN * 64 * 4); // packed bf16 relu output
  unsigned* Ab     = (unsigned*)alloc((size_t)NN * 64 * 4); // packed bf16 layer-0 GEMM input
  unsigned* Bb     = (unsigned*)alloc((size_t)NN * 64 * 4); // packed bf16 H@W (gather src)
  int2*     ecw    = (int2*)alloc((size_t)EE * 8);
  float*    dinv   = (float*)alloc((size_t)NN * 4);
  int*      rowptr = (int*)alloc((size_t)(NN + 1) * 4);
  int*      bsum   = (int*)alloc((size_t)NSCB * 4);
  int*      gstart = (int*)alloc((size_t)(GG + 1) * 4);
  uint4*    Wf     = (uint4*)alloc((size_t)4096 * 16);      // MFMA W fragments (hi/lo), one layer
  float*    z1     = (float*)alloc((size_t)GG * FF * 4);
  float*    bnscL  = (float*)alloc((size_t)LL * 256 * 4);   // per-layer BN (sc, sh)
  float*    basebf = (float*)alloc(128 * 4);                // sh @ W_{t+1}
  float*    zsc    = (float*)alloc(256 * 4);
  (void)ws_size; (void)in_sizes; (void)n_in; (void)out_size;

  hipMemsetAsync(d_ws, 0, zero_bytes, stream);

  k_deg<<<(EE + 255) / 256, 256, 0, stream>>>(ei + EE, deg);
  k_bsum<<<NSCB, 256, 0, stream>>>(deg, bsum, dinv);
  k_rowptr<<<NSCB, 256, 0, stream>>>(deg, bsum, rowptr);
  k_fill<<<(EE + 255) / 256, 256, 0, stream>>>(ei, rowptr, cnt, dinv, ecw);
  k_cvt<<<(NN * 64 + 255) / 256, 256, 0, stream>>>(x, batch, Ab, gstart);
  k_wcvt<<<16, 256, 0, stream>>>(Ws, Wf);

  for (int t = 0; t < LL; ++t) {
    k_mm<<<(NN + 63) / 64, 256, 0, stream>>>(t == 0 ? Ab : Ar, Wf, Bb);
    k_agg<<<AGG_BLOCKS, 256, 0, stream>>>(Bb, rowptr, ecw, bs + t * FF,
                                          t == 0 ? zbase : basebf, batch,
                                          Ar, bnbuf + t * 256, pooled + t * FF);
    if (t < LL - 1) {
      k_post<<<17, 256, 0, stream>>>(bnbuf + t * 256, gammas + t * FF, betas + t * FF,
                                     bnscL + t * 256, Ws + (size_t)(t + 1) * 16384,
                                     Wf, basebf);
    } else {
      k_post<<<1, 256, 0, stream>>>(bnbuf + t * 256, gammas + t * FF, betas + t * FF,
                                    bnscL + t * 256, nullptr, nullptr, nullptr);
    }
  }

  k_z1<<<GG, 128, 0, stream>>>(pooled, bnscL, gstart, W1, b1, z1);
  k_zstat<<<1, 1024, 0, stream>>>(z1, g1, bt1, zsc);
  k_out<<<GG, 128, 0, stream>>>(z1, zsc, W2, b2, out);
}